// Round 5
// baseline (183.163 us; speedup 1.0000x reference)
//
#include <hip/hip_runtime.h>
#include <hip/hip_bf16.h>

#define TLEN 4096
#define NINP 256
#define DD   64

// 1/sqrt(64) * log2(e): folded into WqT so softmax = exp2(s)
#define QSCALE 0.18033688011112042f

typedef __attribute__((ext_vector_type(8))) short bf16x8;
typedef __attribute__((ext_vector_type(4))) float f32x4;

union U8 { bf16x8 v; uint u[4]; };
union F32U { float f; uint u; };

__device__ inline ushort bfu(float x) {           // fp32 -> bf16 RNE
    F32U a; a.f = x;
    uint r = a.u + 0x7fffu + ((a.u >> 16) & 1u);
    return (ushort)(r >> 16);
}
// pack two positive-finite f32 -> bf16 pair (round-half-up): 3 VALU ops
__device__ inline uint pk2(float p0, float p1) {
    F32U a, b; a.f = p0; b.f = p1;
    return __builtin_amdgcn_perm(b.u + 0x8000u, a.u + 0x8000u, 0x07060302u);
}
__device__ inline bf16x8 ld16(const ushort* p) {  // 16B-aligned
    return *(const bf16x8*)p;
}
__device__ inline bf16x8 ld8x2(const ushort* p) { // 8B-aligned (padded LDS)
    U8 u;
    uint2 a = *(const uint2*)p;
    uint2 b = *(const uint2*)(p + 4);
    u.u[0] = a.x; u.u[1] = a.y; u.u[2] = b.x; u.u[3] = b.y;
    return u.v;
}

// ---------------------------------------------------------------------------
// prep: WT[m][d][k] = W_m[k][d] bf16 (Wq scaled), + zero sync counters.
// ---------------------------------------------------------------------------
__global__ __launch_bounds__(256) void prep_wt(
    const float* __restrict__ Wq, const float* __restrict__ Wk,
    const float* __restrict__ Wv, ushort* __restrict__ WT, uint* __restrict__ cnt)
{
    if (blockIdx.x == 0 && threadIdx.x < 8) cnt[threadIdx.x] = 0;
    const int t = threadIdx.x;                 // = k
    const int m = blockIdx.x >> 4;
    const int d0 = (blockIdx.x & 15) * 4;
    const float* W = (m == 0) ? Wq : ((m == 1) ? Wk : Wv);
    const float scale = (m == 0) ? QSCALE : 1.0f;
    float4 v = *(const float4*)&W[t * DD + d0];
    WT[m * 16384 + (d0 + 0) * 256 + t] = bfu(v.x * scale);
    WT[m * 16384 + (d0 + 1) * 256 + t] = bfu(v.y * scale);
    WT[m * 16384 + (d0 + 2) * 256 + t] = bfu(v.z * scale);
    WT[m * 16384 + (d0 + 3) * 256 + t] = bfu(v.w * scale);
}

// Phase-overlapped LDS (max ~50.7 KB -> >=1 block/CU, 256 blocks always resident)
union SMem {
    struct { ushort Wl[64 * 260]; ushort tb[64 * 68]; } a;            // qkv
    struct { ushort Pb[4][32 * 68]; float Ob[4][2048]; float lb[4][32]; } b; // attn
};

template <bool MASK>
__device__ inline void softmax_store(
    f32x4 st[2][4], ushort* Pw, int qb, int c0, int l15, int quad, float* l_acc)
{
    #pragma unroll
    for (int qt = 0; qt < 2; ++qt) {
        const int q = qb + qt * 16 + l15;
        #pragma unroll
        for (int kt = 0; kt < 4; ++kt) {
            const int kbase = c0 + kt * 16 + quad * 4;
            float p[4];
            #pragma unroll
            for (int r = 0; r < 4; ++r) {
                float e = exp2f(st[qt][kt][r]);
                p[r] = (!MASK || (kbase + r <= q)) ? e : 0.f;
                l_acc[qt] += p[r];
            }
            ushort* pw = Pw + (qt * 16 + l15) * 68 + kt * 16 + quad * 4;
            *(uint*)&pw[0] = pk2(p[0], p[1]);
            *(uint*)&pw[2] = pk2(p[2], p[3]);
        }
    }
}

// ---------------------------------------------------------------------------
// Fused, REGULAR launch (grid 256 <= resident capacity -> spin is deadlock-free).
// Phase 1: QKV for rows blk*64..+63 -> Qh,Kh row-major bf16 + VhT[d][t].
// Phase 2: device-scope release (threadfence + atomic add), acquire spin until
//          this batch's 64 producer blocks are done, then acquire fence.
// Phase 3: attention snake pair (tile pr, 127-pr), 4 waves, key-split 4,
//          in-block combine.
// ---------------------------------------------------------------------------
__global__ __launch_bounds__(256, 1) void fused_kernel(
    const float* __restrict__ y, const ushort* __restrict__ WT,
    ushort* __restrict__ Qh, ushort* __restrict__ Kh, ushort* __restrict__ VhT,
    float* __restrict__ out, uint* __restrict__ cnt)
{
    __shared__ SMem sm;
    const int t = threadIdx.x;
    const int w = t >> 6, lane = t & 63;
    const int quad = lane >> 4, l15 = lane & 15;
    const int blk = blockIdx.x;
    const int b = blk >> 6, pr = blk & 63;

    // ================= phase 1: QKV =================
    {
        const int rowbase = blk * 64;
        const int myrow = rowbase + w * 16 + l15;

        bf16x8 afrag[8];
        const float* yrow = y + (size_t)myrow * NINP;
        #pragma unroll
        for (int s = 0; s < 8; ++s) {
            float4 lo = *(const float4*)&yrow[s * 32 + quad * 8];
            float4 hi = *(const float4*)&yrow[s * 32 + quad * 8 + 4];
            U8 u;
            u.u[0] = bfu(lo.x) | (uint(bfu(lo.y)) << 16);
            u.u[1] = bfu(lo.z) | (uint(bfu(lo.w)) << 16);
            u.u[2] = bfu(hi.x) | (uint(bfu(hi.y)) << 16);
            u.u[3] = bfu(hi.z) | (uint(bfu(hi.w)) << 16);
            afrag[s] = u.v;
        }

        f32x4 acc[3][4];
        #pragma unroll
        for (int m = 0; m < 3; ++m)
            #pragma unroll
            for (int nt = 0; nt < 4; ++nt)
                acc[m][nt] = f32x4{0.f, 0.f, 0.f, 0.f};

        for (int m = 0; m < 3; ++m) {
            __syncthreads();
            {   // stage WT[m] (32 KB) into padded LDS
                int n = t >> 2, seg = t & 3;
                const ushort* src = WT + m * 16384 + n * 256 + seg * 64;
                ushort* dst = &sm.a.Wl[n * 260 + seg * 64];
                #pragma unroll
                for (int j = 0; j < 16; ++j)
                    ((uint2*)dst)[j] = ((const uint2*)src)[j];
            }
            __syncthreads();
            #pragma unroll
            for (int s = 0; s < 8; ++s)
                #pragma unroll
                for (int nt = 0; nt < 4; ++nt) {
                    bf16x8 bfrag = ld8x2(&sm.a.Wl[(nt * 16 + l15) * 260 + s * 32 + quad * 8]);
                    acc[m][nt] = __builtin_amdgcn_mfma_f32_16x16x32_bf16(
                        afrag[s], bfrag, acc[m][nt], 0, 0, 0);
                }
        }

        // Q then K epilogue (row-major bf16 via LDS repack)
        for (int m = 0; m < 2; ++m) {
            __syncthreads();
            #pragma unroll
            for (int nt = 0; nt < 4; ++nt)
                #pragma unroll
                for (int r = 0; r < 4; ++r)
                    sm.a.tb[(w * 16 + quad * 4 + r) * 68 + nt * 16 + l15] = bfu(acc[m][nt][r]);
            __syncthreads();
            int row = t >> 2, seg = t & 3;
            ushort* gd = (m == 0 ? Qh : Kh) + (size_t)(rowbase + row) * DD + seg * 16;
            const ushort* sp = &sm.a.tb[row * 68 + seg * 16];
            #pragma unroll
            for (int j = 0; j < 4; ++j) ((uint2*)gd)[j] = ((const uint2*)sp)[j];
        }

        // V^T epilogue
        __syncthreads();
        #pragma unroll
        for (int nt = 0; nt < 4; ++nt) {
            int d = nt * 16 + l15;
            #pragma unroll
            for (int r = 0; r < 4; r += 2) {
                int tt = w * 16 + quad * 4 + r;
                *(uint*)&sm.a.tb[d * 68 + tt] = pk2(acc[2][nt][r], acc[2][nt][r + 1]);
            }
        }
        __syncthreads();
        {
            int d = t >> 2, seg = t & 3;
            int trow = pr * 64 + seg * 16;
            ushort* gv = VhT + ((size_t)b * DD + d) * TLEN + trow;
            const ushort* sp = &sm.a.tb[d * 68 + seg * 16];
            #pragma unroll
            for (int j = 0; j < 4; ++j) ((uint2*)gv)[j] = ((const uint2*)sp)[j];
        }
    }

    // ================= phase 2: publish + spin (device scope) =================
    __threadfence();            // release: drain stores, make visible device-wide
    __syncthreads();
    if (t == 0) {
        __hip_atomic_fetch_add(&cnt[b], 1u, __ATOMIC_RELEASE, __HIP_MEMORY_SCOPE_AGENT);
        while (__hip_atomic_load(&cnt[b], __ATOMIC_ACQUIRE, __HIP_MEMORY_SCOPE_AGENT) < 64u)
            __builtin_amdgcn_s_sleep(8);
    }
    __syncthreads();
    // every thread: acquire so subsequent normal loads see fresh Q/K/V
    (void)__hip_atomic_load(&cnt[b], __ATOMIC_ACQUIRE, __HIP_MEMORY_SCOPE_AGENT);
    __threadfence();            // belt-and-suspenders acquire fence (L1/L2 inv)

    // ================= phase 3: attention =================
    const ushort* Qb = Qh + (size_t)b * TLEN * DD;
    const ushort* Kb = Kh + (size_t)b * TLEN * DD;
    const ushort* Vb = VhT + (size_t)b * DD * TLEN;
    float* outb = out + (size_t)b * TLEN * DD;

    for (int half = 0; half < 2; ++half) {
        const int tile = (half == 0) ? pr : (127 - pr);
        const int seg  = (half == 0) ? w : (3 - w);
        const int qb   = tile * 32;
        const int nc   = (tile + 2) >> 1;        // 64-key chunks (last masked)
        const int cps  = (nc + 3) >> 2;
        const int clo  = seg * cps;
        const int chi  = (nc < clo + cps) ? nc : (clo + cps);

        f32x4 o_acc[2][4];
        #pragma unroll
        for (int qt = 0; qt < 2; ++qt)
            #pragma unroll
            for (int nt = 0; nt < 4; ++nt)
                o_acc[qt][nt] = f32x4{0.f, 0.f, 0.f, 0.f};
        float l_acc[2] = {0.f, 0.f};

        if (clo < chi) {
            bf16x8 qf[2][2];
            #pragma unroll
            for (int qt = 0; qt < 2; ++qt)
                #pragma unroll
                for (int s = 0; s < 2; ++s)
                    qf[qt][s] = ld16(Qb + (size_t)(qb + qt * 16 + l15) * DD + s * 32 + quad * 8);

            bf16x8 kf[4][2];
            {
                int c0 = clo * 64;
                #pragma unroll
                for (int kt = 0; kt < 4; ++kt)
                    #pragma unroll
                    for (int s = 0; s < 2; ++s)
                        kf[kt][s] = ld16(Kb + (size_t)(c0 + kt * 16 + l15) * DD + s * 32 + quad * 8);
            }

            for (int ci = clo; ci < chi; ++ci) {
                const int c0 = ci * 64;
                bf16x8 vf[4][2];
                #pragma unroll
                for (int nt = 0; nt < 4; ++nt)
                    #pragma unroll
                    for (int s = 0; s < 2; ++s)
                        vf[nt][s] = ld16(Vb + (size_t)(nt * 16 + l15) * TLEN + c0 + s * 32 + quad * 8);

                f32x4 st[2][4];
                #pragma unroll
                for (int qt = 0; qt < 2; ++qt)
                    #pragma unroll
                    for (int kt = 0; kt < 4; ++kt)
                        st[qt][kt] = f32x4{0.f, 0.f, 0.f, 0.f};
                #pragma unroll
                for (int s = 0; s < 2; ++s)
                    #pragma unroll
                    for (int qt = 0; qt < 2; ++qt)
                        #pragma unroll
                        for (int kt = 0; kt < 4; ++kt)
                            st[qt][kt] = __builtin_amdgcn_mfma_f32_16x16x32_bf16(
                                kf[kt][s], qf[qt][s], st[qt][kt], 0, 0, 0);

                if (ci + 1 < chi) {
                    int c1 = c0 + 64;
                    #pragma unroll
                    for (int kt = 0; kt < 4; ++kt)
                        #pragma unroll
                        for (int s = 0; s < 2; ++s)
                            kf[kt][s] = ld16(Kb + (size_t)(c1 + kt * 16 + l15) * DD + s * 32 + quad * 8);
                }

                if (ci == nc - 1)
                    softmax_store<true>(st, sm.b.Pb[w], qb, c0, l15, quad, l_acc);
                else
                    softmax_store<false>(st, sm.b.Pb[w], qb, c0, l15, quad, l_acc);

                #pragma unroll
                for (int qt = 0; qt < 2; ++qt) {
                    const ushort* pr_ = &sm.b.Pb[w][(qt * 16 + l15) * 68];
                    bf16x8 ap0 = ld8x2(pr_ + quad * 8);
                    bf16x8 ap1 = ld8x2(pr_ + 32 + quad * 8);
                    #pragma unroll
                    for (int nt = 0; nt < 4; ++nt) {
                        o_acc[qt][nt] = __builtin_amdgcn_mfma_f32_16x16x32_bf16(
                            ap0, vf[nt][0], o_acc[qt][nt], 0, 0, 0);
                        o_acc[qt][nt] = __builtin_amdgcn_mfma_f32_16x16x32_bf16(
                            ap1, vf[nt][1], o_acc[qt][nt], 0, 0, 0);
                    }
                }
            }

            #pragma unroll
            for (int qt = 0; qt < 2; ++qt) {
                l_acc[qt] += __shfl_xor(l_acc[qt], 16, 64);
                l_acc[qt] += __shfl_xor(l_acc[qt], 32, 64);
            }
        }

        // publish partials (zeros if empty task)
        #pragma unroll
        for (int qt = 0; qt < 2; ++qt) {
            #pragma unroll
            for (int nt = 0; nt < 4; ++nt)
                #pragma unroll
                for (int r = 0; r < 4; ++r)
                    sm.b.Ob[w][(qt * 16 + quad * 4 + r) * 64 + nt * 16 + l15] = o_acc[qt][nt][r];
            if (quad == 0) sm.b.lb[w][qt * 16 + l15] = l_acc[qt];
        }
        __syncthreads();

        // 4-way combine + store: thread -> (q = t>>3, d0 = (t&7)*8)
        {
            int q = t >> 3, d0 = (t & 7) * 8;
            f32x4 s0 = f32x4{0.f, 0.f, 0.f, 0.f};
            f32x4 s1 = f32x4{0.f, 0.f, 0.f, 0.f};
            float ls = 0.f;
            #pragma unroll
            for (int ww = 0; ww < 4; ++ww) {
                s0 += *(const f32x4*)&sm.b.Ob[ww][q * 64 + d0];
                s1 += *(const f32x4*)&sm.b.Ob[ww][q * 64 + d0 + 4];
                ls += sm.b.lb[ww][q];
            }
            float inv = __builtin_amdgcn_rcpf(ls);
            float4 r0, r1;
            r0.x = s0[0] * inv; r0.y = s0[1] * inv; r0.z = s0[2] * inv; r0.w = s0[3] * inv;
            r1.x = s1[0] * inv; r1.y = s1[1] * inv; r1.z = s1[2] * inv; r1.w = s1[3] * inv;
            *(float4*)&outb[(size_t)(qb + q) * DD + d0] = r0;
            *(float4*)&outb[(size_t)(qb + q) * DD + d0 + 4] = r1;
        }
        __syncthreads();
    }
}

extern "C" void kernel_launch(void* const* d_in, const int* in_sizes, int n_in,
                              void* d_out, int out_size, void* d_ws, size_t ws_size,
                              hipStream_t stream) {
    const float* y  = (const float*)d_in[0];
    const float* Wq = (const float*)d_in[1];
    const float* Wk = (const float*)d_in[2];
    const float* Wv = (const float*)d_in[3];
    float* outp = (float*)d_out;

    const int rows = in_sizes[0] / NINP;       // B*T = 16384
    const int nb = rows / TLEN;                // batches = 4

    ushort* WT  = (ushort*)d_ws;               // 3*16384 bf16
    ushort* Qh  = WT + 3 * 16384;
    ushort* Kh  = Qh + (size_t)rows * DD;
    ushort* VhT = Kh + (size_t)rows * DD;      // [b][d][t]
    uint*   cnt = (uint*)(VhT + (size_t)rows * DD);

    prep_wt<<<48, 256, 0, stream>>>(Wq, Wk, Wv, WT, cnt);
    fused_kernel<<<nb * 64, 256, 0, stream>>>(y, WT, Qh, Kh, VhT, outp, cnt);
}

// Round 6
// 116.512 us; speedup vs baseline: 1.5721x; 1.5721x over previous
//
#include <hip/hip_runtime.h>
#include <hip/hip_bf16.h>

#define TLEN 4096
#define NINP 256
#define DD   64

// 1/sqrt(64) * log2(e): folded into WqT so softmax = exp2(s)
#define QSCALE 0.18033688011112042f

typedef __attribute__((ext_vector_type(8))) short bf16x8;
typedef __attribute__((ext_vector_type(4))) float f32x4;

union U8 { bf16x8 v; uint u[4]; };
union F32U { float f; uint u; };

__device__ inline ushort bfu(float x) {           // fp32 -> bf16 RNE
    F32U a; a.f = x;
    uint r = a.u + 0x7fffu + ((a.u >> 16) & 1u);
    return (ushort)(r >> 16);
}
// pack two positive-finite f32 -> bf16 pair (round-half-up): 3 VALU ops
__device__ inline uint pk2(float p0, float p1) {
    F32U a, b; a.f = p0; b.f = p1;
    return __builtin_amdgcn_perm(b.u + 0x8000u, a.u + 0x8000u, 0x07060302u);
}
__device__ inline bf16x8 ld16(const ushort* p) {  // 16B-aligned
    return *(const bf16x8*)p;
}
__device__ inline bf16x8 ld8x2(const ushort* p) { // 8B-aligned (padded LDS)
    U8 u;
    uint2 a = *(const uint2*)p;
    uint2 b = *(const uint2*)(p + 4);
    u.u[0] = a.x; u.u[1] = a.y; u.u[2] = b.x; u.u[3] = b.y;
    return u.v;
}

// ---------------------------------------------------------------------------
// prep: WT[m][d][k] = W_m[k][d] bf16 (Wq scaled). 48 blocks.
// ---------------------------------------------------------------------------
__global__ __launch_bounds__(256) void prep_wt(
    const float* __restrict__ Wq, const float* __restrict__ Wk,
    const float* __restrict__ Wv, ushort* __restrict__ WT)
{
    const int t = threadIdx.x;                 // = k
    const int m = blockIdx.x >> 4;
    const int d0 = (blockIdx.x & 15) * 4;
    const float* W = (m == 0) ? Wq : ((m == 1) ? Wk : Wv);
    const float scale = (m == 0) ? QSCALE : 1.0f;
    float4 v = *(const float4*)&W[t * DD + d0];
    WT[m * 16384 + (d0 + 0) * 256 + t] = bfu(v.x * scale);
    WT[m * 16384 + (d0 + 1) * 256 + t] = bfu(v.y * scale);
    WT[m * 16384 + (d0 + 2) * 256 + t] = bfu(v.z * scale);
    WT[m * 16384 + (d0 + 3) * 256 + t] = bfu(v.w * scale);
}

// ---------------------------------------------------------------------------
// QKV: MFMA bf16. 512 blocks x 32 rows (2/CU). (identical to R3 — passed)
// ---------------------------------------------------------------------------
__global__ __launch_bounds__(256, 2) void qkv_kernel(
    const float* __restrict__ y, const ushort* __restrict__ WT,
    ushort* __restrict__ Qh, ushort* __restrict__ Kh, ushort* __restrict__ VhT)
{
    __shared__ ushort Wl[64 * 260];
    __shared__ ushort tb[2304];

    const int t = threadIdx.x;
    const int w = t >> 6, lane = t & 63;
    const int quad = lane >> 4, l15 = lane & 15;
    const int rgrp = w & 1, ngrp = w >> 1;
    const int rowbase = blockIdx.x * 32;
    const int myrow = rowbase + rgrp * 16 + l15;

    bf16x8 afrag[8];
    const float* yrow = y + (size_t)myrow * NINP;
    #pragma unroll
    for (int s = 0; s < 8; ++s) {
        float4 lo = *(const float4*)&yrow[s * 32 + quad * 8];
        float4 hi = *(const float4*)&yrow[s * 32 + quad * 8 + 4];
        U8 u;
        u.u[0] = bfu(lo.x) | (uint(bfu(lo.y)) << 16);
        u.u[1] = bfu(lo.z) | (uint(bfu(lo.w)) << 16);
        u.u[2] = bfu(hi.x) | (uint(bfu(hi.y)) << 16);
        u.u[3] = bfu(hi.z) | (uint(bfu(hi.w)) << 16);
        afrag[s] = u.v;
    }

    f32x4 acc[3][2];
    #pragma unroll
    for (int m = 0; m < 3; ++m)
        #pragma unroll
        for (int nj = 0; nj < 2; ++nj)
            acc[m][nj] = f32x4{0.f, 0.f, 0.f, 0.f};

    for (int m = 0; m < 3; ++m) {
        __syncthreads();
        {
            int n = t >> 2, seg = t & 3;
            const ushort* src = WT + m * 16384 + n * 256 + seg * 64;
            ushort* dst = &Wl[n * 260 + seg * 64];
            #pragma unroll
            for (int j = 0; j < 16; ++j)
                ((uint2*)dst)[j] = ((const uint2*)src)[j];
        }
        __syncthreads();
        #pragma unroll
        for (int s = 0; s < 8; ++s)
            #pragma unroll
            for (int nj = 0; nj < 2; ++nj) {
                int nt = ngrp * 2 + nj;
                bf16x8 bfrag = ld8x2(&Wl[(nt * 16 + l15) * 260 + s * 32 + quad * 8]);
                acc[m][nj] = __builtin_amdgcn_mfma_f32_16x16x32_bf16(
                    afrag[s], bfrag, acc[m][nj], 0, 0, 0);
            }
    }

    for (int m = 0; m < 2; ++m) {
        __syncthreads();
        #pragma unroll
        for (int nj = 0; nj < 2; ++nj) {
            int nt = ngrp * 2 + nj;
            #pragma unroll
            for (int r = 0; r < 4; ++r)
                tb[(rgrp * 16 + quad * 4 + r) * 68 + nt * 16 + l15] = bfu(acc[m][nj][r]);
        }
        __syncthreads();
        int row = t >> 3, c0 = (t & 7) * 8;
        ushort* gd = (m == 0 ? Qh : Kh) + (size_t)(rowbase + row) * DD + c0;
        const ushort* sp = &tb[row * 68 + c0];
        ((uint2*)gd)[0] = ((const uint2*)sp)[0];
        ((uint2*)gd)[1] = ((const uint2*)sp)[1];
    }

    __syncthreads();
    #pragma unroll
    for (int nj = 0; nj < 2; ++nj) {
        int nt = ngrp * 2 + nj;
        int d = nt * 16 + l15;
        #pragma unroll
        for (int r = 0; r < 4; r += 2) {
            int tt = rgrp * 16 + quad * 4 + r;
            *(uint*)&tb[d * 36 + tt] = pk2(acc[2][nj][r], acc[2][nj][r + 1]);
        }
    }
    __syncthreads();
    {
        int d = t >> 2, seg = t & 3;
        int bb = blockIdx.x >> 7;
        int tofs = (blockIdx.x & 127) * 32 + seg * 8;
        ushort* gv = VhT + ((size_t)bb * DD + d) * TLEN + tofs;
        const ushort* sp = &tb[d * 36 + seg * 8];
        ((uint2*)gv)[0] = ((const uint2*)sp)[0];
        ((uint2*)gv)[1] = ((const uint2*)sp)[1];
    }
}

// ---------------------------------------------------------------------------
// Attention (flash-style, coalesced LDS staging).
// Block = one 32-q tile; grid 512 (batch = blk&3, tile = 127-(blk>>2): big
// tiles dispatched first). 4 waves: wave (qt=w>>1, g=w&1) owns 16 queries x
// 32 keys of every 64-key chunk. K/V chunk staged coalesced into padded LDS
// (VGPR prefetch of chunk c+1 during compute of c). S^T = K.Q^T (4 MFMA),
// exp2 softmax (no max; logits O(1)), P via wave-private LDS -> A-frag,
// O += P.V (4 MFMA, K=32). 2-way O combine (g pairs) at the end.
// ---------------------------------------------------------------------------
__global__ __launch_bounds__(256, 4) void attn_kernel(
    const ushort* __restrict__ Qh, const ushort* __restrict__ Kh,
    const ushort* __restrict__ VhT, float* __restrict__ out)
{
    __shared__ ushort Kl[64 * 72];      // [key][d] padded   (9.2 KB)
    __shared__ ushort Vt[64 * 72];      // [d][key] padded   (9.2 KB)
    __shared__ ushort Pw[4][16 * 36];   // per-wave P [q][k] (4.6 KB)
    __shared__ float  Ob[2][16 * 64];   // per-qt partial O  (8 KB)
    __shared__ float  lb[2][2][16];     // [g][qt][q]

    const int t = threadIdx.x;
    const int w = t >> 6, lane = t & 63;
    const int quad = lane >> 4, l15 = lane & 15;
    const int qt = w >> 1, g = w & 1;
    const int blk = blockIdx.x;
    const int batch = blk & 3;
    const int tile = 127 - (blk >> 2);          // big tiles first
    const int qb = tile * 32;
    const int nc = (tile + 2) >> 1;             // 64-key chunks (last masked)

    const ushort* Qb = Qh + (size_t)batch * TLEN * DD;
    const ushort* Kb = Kh + (size_t)batch * TLEN * DD;
    const ushort* Vb = VhT + (size_t)batch * DD * TLEN;
    float* outb = out + (size_t)batch * TLEN * DD;

    // Q B-fragments (once per block): B[kk=d][n=q=l15]
    bf16x8 qf[2];
    #pragma unroll
    for (int s = 0; s < 2; ++s)
        qf[s] = ld16(Qb + (size_t)(qb + qt * 16 + l15) * DD + s * 32 + quad * 8);

    // staging role: thread t handles rows srow, srow+32; 16B segment sseg
    const int srow = t >> 3, sseg = t & 7;

    f32x4 o_acc[4];
    #pragma unroll
    for (int nt = 0; nt < 4; ++nt) o_acc[nt] = f32x4{0.f, 0.f, 0.f, 0.f};
    float l_acc = 0.f;

    // prefetch chunk 0 into VGPRs (fully coalesced 16B loads)
    uint4 ka, kb4, va, vb4;
    {
        const ushort* kp = Kb + (size_t)srow * DD + sseg * 8;
        ka  = *(const uint4*)kp;
        kb4 = *(const uint4*)(kp + 32 * DD);
        const ushort* vp = Vb + (size_t)srow * TLEN + sseg * 8;
        va  = *(const uint4*)vp;
        vb4 = *(const uint4*)(vp + 32 * TLEN);
    }

    for (int ci = 0; ci < nc; ++ci) {
        const int c0 = ci * 64;
        __syncthreads();                        // prev chunk fully consumed
        *(uint4*)&Kl[srow * 72 + sseg * 8]        = ka;
        *(uint4*)&Kl[(srow + 32) * 72 + sseg * 8] = kb4;
        *(uint4*)&Vt[srow * 72 + sseg * 8]        = va;
        *(uint4*)&Vt[(srow + 32) * 72 + sseg * 8] = vb4;
        __syncthreads();

        if (ci + 1 < nc) {                      // prefetch next chunk
            const int c1 = c0 + 64;
            const ushort* kp = Kb + (size_t)(c1 + srow) * DD + sseg * 8;
            ka  = *(const uint4*)kp;
            kb4 = *(const uint4*)(kp + 32 * DD);
            const ushort* vp = Vb + (size_t)srow * TLEN + c1 + sseg * 8;
            va  = *(const uint4*)vp;
            vb4 = *(const uint4*)(vp + 32 * TLEN);
        }

        // K A-fragments from LDS: A[m=key][kk=d]
        bf16x8 kf[2][2];
        #pragma unroll
        for (int kt2 = 0; kt2 < 2; ++kt2)
            #pragma unroll
            for (int s = 0; s < 2; ++s)
                kf[kt2][s] = ld16(&Kl[(g * 32 + kt2 * 16 + l15) * 72 + s * 32 + quad * 8]);

        // S^T: rows = keys, cols = queries
        f32x4 st[2];
        st[0] = f32x4{0.f, 0.f, 0.f, 0.f};
        st[1] = f32x4{0.f, 0.f, 0.f, 0.f};
        #pragma unroll
        for (int s = 0; s < 2; ++s)
            #pragma unroll
            for (int kt2 = 0; kt2 < 2; ++kt2)
                st[kt2] = __builtin_amdgcn_mfma_f32_16x16x32_bf16(
                    kf[kt2][s], qf[s], st[kt2], 0, 0, 0);

        // V B-fragments: B[kk=key][n=d]
        bf16x8 vf[4];
        #pragma unroll
        for (int nt = 0; nt < 4; ++nt)
            vf[nt] = ld16(&Vt[(nt * 16 + l15) * 72 + g * 32 + quad * 8]);

        // softmax weights -> Pw (wave-private)
        ushort* pwb = &Pw[w][l15 * 36 + quad * 4];
        if (ci == nc - 1) {
            const int q = qb + qt * 16 + l15;
            #pragma unroll
            for (int kt2 = 0; kt2 < 2; ++kt2) {
                const int kbase = c0 + g * 32 + kt2 * 16 + quad * 4;
                float p[4];
                #pragma unroll
                for (int r = 0; r < 4; ++r) {
                    float e = exp2f(st[kt2][r]);
                    p[r] = (kbase + r <= q) ? e : 0.f;
                    l_acc += p[r];
                }
                *(uint*)&pwb[kt2 * 16]     = pk2(p[0], p[1]);
                *(uint*)&pwb[kt2 * 16 + 2] = pk2(p[2], p[3]);
            }
        } else {
            #pragma unroll
            for (int kt2 = 0; kt2 < 2; ++kt2) {
                float p[4];
                #pragma unroll
                for (int r = 0; r < 4; ++r) {
                    p[r] = exp2f(st[kt2][r]);
                    l_acc += p[r];
                }
                *(uint*)&pwb[kt2 * 16]     = pk2(p[0], p[1]);
                *(uint*)&pwb[kt2 * 16 + 2] = pk2(p[2], p[3]);
            }
        }

        // O += P.V  (A[m=q][kk=key 0..31] — one ld8x2 covers K=32)
        bf16x8 ap = ld8x2(&Pw[w][l15 * 36 + quad * 8]);
        #pragma unroll
        for (int nt = 0; nt < 4; ++nt)
            o_acc[nt] = __builtin_amdgcn_mfma_f32_16x16x32_bf16(
                ap, vf[nt], o_acc[nt], 0, 0, 0);
    }

    // l: sum across quads (lanes with same l15 hold partials for q=l15)
    l_acc += __shfl_xor(l_acc, 16, 64);
    l_acc += __shfl_xor(l_acc, 32, 64);
    if (quad == 0) lb[g][qt][l15] = l_acc;

    // O partial publish (g=1) and combine (g=0)
    if (g == 1) {
        #pragma unroll
        for (int nt = 0; nt < 4; ++nt)
            #pragma unroll
            for (int r = 0; r < 4; ++r)
                Ob[qt][(quad * 4 + r) * 64 + nt * 16 + l15] = o_acc[nt][r];
    }
    __syncthreads();
    if (g == 0) {
        float linv[4];
        #pragma unroll
        for (int r = 0; r < 4; ++r) {
            int q16 = quad * 4 + r;
            linv[r] = __builtin_amdgcn_rcpf(lb[0][qt][q16] + lb[1][qt][q16]);
        }
        #pragma unroll
        for (int nt = 0; nt < 4; ++nt)
            #pragma unroll
            for (int r = 0; r < 4; ++r) {
                float v = o_acc[nt][r] + Ob[qt][(quad * 4 + r) * 64 + nt * 16 + l15];
                outb[(size_t)(qb + qt * 16 + quad * 4 + r) * DD + nt * 16 + l15] = v * linv[r];
            }
    }
}

extern "C" void kernel_launch(void* const* d_in, const int* in_sizes, int n_in,
                              void* d_out, int out_size, void* d_ws, size_t ws_size,
                              hipStream_t stream) {
    const float* y  = (const float*)d_in[0];
    const float* Wq = (const float*)d_in[1];
    const float* Wk = (const float*)d_in[2];
    const float* Wv = (const float*)d_in[3];
    float* outp = (float*)d_out;

    const int rows = in_sizes[0] / NINP;       // B*T = 16384
    const int nb = rows / TLEN;                // batches = 4

    ushort* WT  = (ushort*)d_ws;               // 3*16384 bf16
    ushort* Qh  = WT + 3 * 16384;
    ushort* Kh  = Qh + (size_t)rows * DD;
    ushort* VhT = Kh + (size_t)rows * DD;      // [b][d][t]

    prep_wt<<<48, 256, 0, stream>>>(Wq, Wk, Wv, WT);
    qkv_kernel<<<rows / 32, 256, 0, stream>>>(y, WT, Qh, Kh, VhT);
    attn_kernel<<<nb * 128, 256, 0, stream>>>(Qh, Kh, VhT, outp);
}